// Round 2
// baseline (159.298 us; speedup 1.0000x reference)
//
#include <hip/hip_runtime.h>
#include <stdint.h>

// out = dequant( int8(lhs*ls) @ int8(rhs*rs) ) / (ls*rs), 4096^3, fp32 in/out.
// ls = 127 / max(amax|lhs|, 1e-12). Int core is bit-exact vs numpy (RNE quant).
//
// Workspace: [0,16Mi) qA int8 MxK ; [16Mi,32Mi) qBT int8 NxK ; then 2x u32 amax bits.
//
// GEMM v3: same geometry/ring/addressing as v2 (256x256 tile, 8 waves 2Mx4N,
// BK=64, 3-deep LDS ring, counted vmcnt(4), pre-swizzled conflict-free frag
// reads) but the K-loop is the m201-style FINE per-phase interleave: each
// K-tile is 4 phases of {ds_read subtile + 1 global_load_lds -> barrier ->
// 8 MFMA -> barrier}. v2's single-barrier coarse body serialized the LDS-read
// window (~1150 cyc/CU/tile) against the MFMA window (~1300 cyc) in lockstep;
// per-phase barriers let the two pipes overlap across waves (m196/m218 lever).

#define NROW 4096
#define NELEM (4096 * 4096)

typedef __attribute__((ext_vector_type(4))) int int32x4;
typedef const __attribute__((address_space(1))) int8_t* gptr1_t;
typedef __attribute__((address_space(3))) int8_t* lptr3_t;

__global__ void absmax_both_kernel(const float* __restrict__ lhs,
                                   const float* __restrict__ rhs,
                                   unsigned* __restrict__ amax) {
    __shared__ float red[4];
    const int t = blockIdx.x & 1;
    const float4* x4 = (const float4*)(t ? rhs : lhs);
    const int bid = blockIdx.x >> 1;
    const int stride = (gridDim.x >> 1) * blockDim.x;  // 262144
    int i = bid * blockDim.x + threadIdx.x;
    float m0 = 0.0f, m1 = 0.0f, m2 = 0.0f, m3 = 0.0f;
    for (; i + 3 * stride < NELEM / 4; i += 4 * stride) {
        float4 a = x4[i];
        float4 b = x4[i + stride];
        float4 c = x4[i + 2 * stride];
        float4 d = x4[i + 3 * stride];
        m0 = fmaxf(m0, fmaxf(fmaxf(fabsf(a.x), fabsf(a.y)),
                             fmaxf(fabsf(a.z), fabsf(a.w))));
        m1 = fmaxf(m1, fmaxf(fmaxf(fabsf(b.x), fabsf(b.y)),
                             fmaxf(fabsf(b.z), fabsf(b.w))));
        m2 = fmaxf(m2, fmaxf(fmaxf(fabsf(c.x), fabsf(c.y)),
                             fmaxf(fabsf(c.z), fabsf(c.w))));
        m3 = fmaxf(m3, fmaxf(fmaxf(fabsf(d.x), fabsf(d.y)),
                             fmaxf(fabsf(d.z), fabsf(d.w))));
    }
    for (; i < NELEM / 4; i += stride) {
        float4 a = x4[i];
        m0 = fmaxf(m0, fmaxf(fmaxf(fabsf(a.x), fabsf(a.y)),
                             fmaxf(fabsf(a.z), fabsf(a.w))));
    }
    float m = fmaxf(fmaxf(m0, m1), fmaxf(m2, m3));
    for (int off = 32; off > 0; off >>= 1)
        m = fmaxf(m, __shfl_down(m, off, 64));
    const int lane = threadIdx.x & 63, wave = threadIdx.x >> 6;
    if (lane == 0) red[wave] = m;
    __syncthreads();
    if (threadIdx.x == 0) {
        float b = fmaxf(fmaxf(red[0], red[1]), fmaxf(red[2], red[3]));
        atomicMax(amax + t, __float_as_uint(b));  // |x|>=0: bits monotone as uint
    }
}

__device__ __forceinline__ int q8(float v, float s) {
    int r = __float2int_rn(v * s);  // RNE, matches jnp.round
    r = r < -127 ? -127 : r;
    r = r > 127 ? 127 : r;
    return r;
}

__global__ void quant_kernel(const float* __restrict__ lhs,
                             const float* __restrict__ rhs,
                             int8_t* __restrict__ qA, int8_t* __restrict__ qT,
                             const unsigned* __restrict__ amax) {
    __shared__ int8_t sm[64][68];
    if (blockIdx.x < 16384) {
        const float s = 127.0f / fmaxf(__uint_as_float(amax[0]), 1e-12f);
        const int i = blockIdx.x * blockDim.x + threadIdx.x;
        float4 v = ((const float4*)lhs)[i];
        int b0 = q8(v.x, s), b1 = q8(v.y, s), b2 = q8(v.z, s), b3 = q8(v.w, s);
        ((int*)qA)[i] = (b0 & 0xff) | ((b1 & 0xff) << 8) | ((b2 & 0xff) << 16)
                      | ((b3 & 0xff) << 24);
    } else {
        const float s = 127.0f / fmaxf(__uint_as_float(amax[1]), 1e-12f);
        const int b = blockIdx.x - 16384;
        const int n0 = (b & 63) * 64, k0 = (b >> 6) * 64;
        const int rl = threadIdx.x >> 4;   // k row within 16-row slab
        const int nq = threadIdx.x & 15;   // float4 column
        for (int r = 0; r < 4; ++r) {
            const int kl = r * 16 + rl;
            float4 v = *(const float4*)(rhs + (size_t)(k0 + kl) * NROW + n0 + nq * 4);
            sm[nq * 4 + 0][kl] = (int8_t)q8(v.x, s);
            sm[nq * 4 + 1][kl] = (int8_t)q8(v.y, s);
            sm[nq * 4 + 2][kl] = (int8_t)q8(v.z, s);
            sm[nq * 4 + 3][kl] = (int8_t)q8(v.w, s);
        }
        __syncthreads();
        const int nl = threadIdx.x >> 2;
        const int kq = threadIdx.x & 3;
        int4 w;
        w.x = *(const int*)&sm[nl][kq * 16 + 0];
        w.y = *(const int*)&sm[nl][kq * 16 + 4];
        w.z = *(const int*)&sm[nl][kq * 16 + 8];
        w.w = *(const int*)&sm[nl][kq * 16 + 12];
        *(int4*)(qT + (size_t)(n0 + nl) * NROW + k0 + kq * 16) = w;
    }
}

// One K-tile iteration, 4 phases. DO_STAGE: issue 1 global_load_lds per
// phase (4 per iter). VMN: 4 = counted retire of tile kt+1's loads (steady
// state); 0 = drain (kt=62); -1 = none (kt=63). vmcnt sits in P3 before the
// pre-MFMA barrier so MFMA+barrier cover any residual latency.
template <bool DO_STAGE, int VMN>
__device__ __forceinline__ void gemm_iter(
    const int8_t* a, const int8_t* b, int aoff, int boff, int32x4 (&acc)[8][4],
    gptr1_t pA0, gptr1_t pA1, gptr1_t pB0, gptr1_t pB1,
    lptr3_t dA0, lptr3_t dA1, lptr3_t dB0, lptr3_t dB1) {
    int32x4 bf0, bf1, bf2, bf3, a0, a1;

    // ---- P0: bf[0..3] + af[0,1] ----
    bf0 = *(const int32x4*)(b + boff);
    bf1 = *(const int32x4*)(b + boff + 1024);
    bf2 = *(const int32x4*)(b + boff + 2048);
    bf3 = *(const int32x4*)(b + boff + 3072);
    a0 = *(const int32x4*)(a + aoff);
    a1 = *(const int32x4*)(a + aoff + 1024);
    if (DO_STAGE) __builtin_amdgcn_global_load_lds(pA0, dA0, 16, 0, 0);
    __builtin_amdgcn_sched_barrier(0);
    __builtin_amdgcn_s_barrier();
    __builtin_amdgcn_s_setprio(1);
    acc[0][0] = __builtin_amdgcn_mfma_i32_16x16x64_i8(a0, bf0, acc[0][0], 0, 0, 0);
    acc[0][1] = __builtin_amdgcn_mfma_i32_16x16x64_i8(a0, bf1, acc[0][1], 0, 0, 0);
    acc[0][2] = __builtin_amdgcn_mfma_i32_16x16x64_i8(a0, bf2, acc[0][2], 0, 0, 0);
    acc[0][3] = __builtin_amdgcn_mfma_i32_16x16x64_i8(a0, bf3, acc[0][3], 0, 0, 0);
    acc[1][0] = __builtin_amdgcn_mfma_i32_16x16x64_i8(a1, bf0, acc[1][0], 0, 0, 0);
    acc[1][1] = __builtin_amdgcn_mfma_i32_16x16x64_i8(a1, bf1, acc[1][1], 0, 0, 0);
    acc[1][2] = __builtin_amdgcn_mfma_i32_16x16x64_i8(a1, bf2, acc[1][2], 0, 0, 0);
    acc[1][3] = __builtin_amdgcn_mfma_i32_16x16x64_i8(a1, bf3, acc[1][3], 0, 0, 0);
    __builtin_amdgcn_s_setprio(0);
    __builtin_amdgcn_s_barrier();

    // ---- P1: af[2,3] ----
    a0 = *(const int32x4*)(a + aoff + 2048);
    a1 = *(const int32x4*)(a + aoff + 3072);
    if (DO_STAGE) __builtin_amdgcn_global_load_lds(pA1, dA1, 16, 0, 0);
    __builtin_amdgcn_sched_barrier(0);
    __builtin_amdgcn_s_barrier();
    __builtin_amdgcn_s_setprio(1);
    acc[2][0] = __builtin_amdgcn_mfma_i32_16x16x64_i8(a0, bf0, acc[2][0], 0, 0, 0);
    acc[2][1] = __builtin_amdgcn_mfma_i32_16x16x64_i8(a0, bf1, acc[2][1], 0, 0, 0);
    acc[2][2] = __builtin_amdgcn_mfma_i32_16x16x64_i8(a0, bf2, acc[2][2], 0, 0, 0);
    acc[2][3] = __builtin_amdgcn_mfma_i32_16x16x64_i8(a0, bf3, acc[2][3], 0, 0, 0);
    acc[3][0] = __builtin_amdgcn_mfma_i32_16x16x64_i8(a1, bf0, acc[3][0], 0, 0, 0);
    acc[3][1] = __builtin_amdgcn_mfma_i32_16x16x64_i8(a1, bf1, acc[3][1], 0, 0, 0);
    acc[3][2] = __builtin_amdgcn_mfma_i32_16x16x64_i8(a1, bf2, acc[3][2], 0, 0, 0);
    acc[3][3] = __builtin_amdgcn_mfma_i32_16x16x64_i8(a1, bf3, acc[3][3], 0, 0, 0);
    __builtin_amdgcn_s_setprio(0);
    __builtin_amdgcn_s_barrier();

    // ---- P2: af[4,5] ----
    a0 = *(const int32x4*)(a + aoff + 4096);
    a1 = *(const int32x4*)(a + aoff + 5120);
    if (DO_STAGE) __builtin_amdgcn_global_load_lds(pB0, dB0, 16, 0, 0);
    __builtin_amdgcn_sched_barrier(0);
    __builtin_amdgcn_s_barrier();
    __builtin_amdgcn_s_setprio(1);
    acc[4][0] = __builtin_amdgcn_mfma_i32_16x16x64_i8(a0, bf0, acc[4][0], 0, 0, 0);
    acc[4][1] = __builtin_amdgcn_mfma_i32_16x16x64_i8(a0, bf1, acc[4][1], 0, 0, 0);
    acc[4][2] = __builtin_amdgcn_mfma_i32_16x16x64_i8(a0, bf2, acc[4][2], 0, 0, 0);
    acc[4][3] = __builtin_amdgcn_mfma_i32_16x16x64_i8(a0, bf3, acc[4][3], 0, 0, 0);
    acc[5][0] = __builtin_amdgcn_mfma_i32_16x16x64_i8(a1, bf0, acc[5][0], 0, 0, 0);
    acc[5][1] = __builtin_amdgcn_mfma_i32_16x16x64_i8(a1, bf1, acc[5][1], 0, 0, 0);
    acc[5][2] = __builtin_amdgcn_mfma_i32_16x16x64_i8(a1, bf2, acc[5][2], 0, 0, 0);
    acc[5][3] = __builtin_amdgcn_mfma_i32_16x16x64_i8(a1, bf3, acc[5][3], 0, 0, 0);
    __builtin_amdgcn_s_setprio(0);
    __builtin_amdgcn_s_barrier();

    // ---- P3: af[6,7] + counted vmcnt ----
    a0 = *(const int32x4*)(a + aoff + 6144);
    a1 = *(const int32x4*)(a + aoff + 7168);
    if (DO_STAGE) __builtin_amdgcn_global_load_lds(pB1, dB1, 16, 0, 0);
    if (VMN == 4) asm volatile("s_waitcnt vmcnt(4)" ::: "memory");
    if (VMN == 0) asm volatile("s_waitcnt vmcnt(0)" ::: "memory");
    __builtin_amdgcn_sched_barrier(0);
    __builtin_amdgcn_s_barrier();
    __builtin_amdgcn_s_setprio(1);
    acc[6][0] = __builtin_amdgcn_mfma_i32_16x16x64_i8(a0, bf0, acc[6][0], 0, 0, 0);
    acc[6][1] = __builtin_amdgcn_mfma_i32_16x16x64_i8(a0, bf1, acc[6][1], 0, 0, 0);
    acc[6][2] = __builtin_amdgcn_mfma_i32_16x16x64_i8(a0, bf2, acc[6][2], 0, 0, 0);
    acc[6][3] = __builtin_amdgcn_mfma_i32_16x16x64_i8(a0, bf3, acc[6][3], 0, 0, 0);
    acc[7][0] = __builtin_amdgcn_mfma_i32_16x16x64_i8(a1, bf0, acc[7][0], 0, 0, 0);
    acc[7][1] = __builtin_amdgcn_mfma_i32_16x16x64_i8(a1, bf1, acc[7][1], 0, 0, 0);
    acc[7][2] = __builtin_amdgcn_mfma_i32_16x16x64_i8(a1, bf2, acc[7][2], 0, 0, 0);
    acc[7][3] = __builtin_amdgcn_mfma_i32_16x16x64_i8(a1, bf3, acc[7][3], 0, 0, 0);
    __builtin_amdgcn_s_setprio(0);
    __builtin_amdgcn_s_barrier();
}

// 256x256 tile, 8 waves, BK=64, 3-buffer LDS ring, counted vmcnt, 4-phase
// fine interleave. Ring invariant at iteration kt: compute reads slot kt%3;
// stage(kt+2) writes slot (kt+2)%3, whose last readers finished at the
// barrier ending iteration kt-1. Per-iter vmcnt(4) retires exactly tile
// kt+1's 4 loads while tile kt+2's 4 remain in flight across barriers.
__global__ __launch_bounds__(512, 2) void gemm_i8_kernel(
    const int8_t* __restrict__ qA, const int8_t* __restrict__ qBT,
    float* __restrict__ out, const unsigned* __restrict__ amax) {
    __shared__ __align__(16) int8_t sA[3][256 * 64];
    __shared__ __align__(16) int8_t sB[3][256 * 64];

    const int tid = threadIdx.x;
    const int lane = tid & 63;
    const int wave = tid >> 6;      // 0..7
    const int wm = wave >> 2;       // 0..1 : 128-row sub-tile
    const int wn = wave & 3;        // 0..3 : 64-col sub-tile
    const int m0 = blockIdx.y * 256, n0 = blockIdx.x * 256;

    const int r = lane & 15;        // row/col within 16
    const int q = lane >> 4;        // K-quad (16 B) within 64

    // Frag read offsets (pos independent of mi/ni: (row+16*mi)>>1 changes by
    // 8*mi == 0 mod 4 -> mi folds into the ds_read immediate offset).
    const int rowA = wm * 128 + r;
    const int aoff = rowA * 64 + ((q + (rowA >> 1)) & 3) * 16;
    const int rowB = wn * 64 + r;
    const int boff = rowB * 64 + ((q + (rowB >> 1)) & 3) * 16;

    // Staging: 1024 16B-chunks per tensor per K-tile, 2 per thread. Linear
    // LDS destination (global_load_lds requirement); global source quad is
    // inverse-swizzled: chunk C -> row C>>2, pos C&3 holds quad (pos-row>>1)&3.
    const int C0 = tid, C1 = tid + 512;
    const int rS0 = C0 >> 2, G0 = ((C0 & 3) - (rS0 >> 1)) & 3;
    const int rS1 = C1 >> 2, G1 = ((C1 & 3) - (rS1 >> 1)) & 3;
    const gptr1_t pA0 = (gptr1_t)(qA + (size_t)(m0 + rS0) * NROW + G0 * 16);
    const gptr1_t pA1 = (gptr1_t)(qA + (size_t)(m0 + rS1) * NROW + G1 * 16);
    const gptr1_t pB0 = (gptr1_t)(qBT + (size_t)(n0 + rS0) * NROW + G0 * 16);
    const gptr1_t pB1 = (gptr1_t)(qBT + (size_t)(n0 + rS1) * NROW + G1 * 16);
    int8_t* sAf = &sA[0][0];
    int8_t* sBf = &sB[0][0];
    const int d0 = C0 * 16, d1 = C1 * 16;

    int32x4 acc[8][4];
#pragma unroll
    for (int mi = 0; mi < 8; ++mi)
#pragma unroll
        for (int ni = 0; ni < 4; ++ni) acc[mi][ni] = (int32x4)(0);

    // Prologue: fill slots 0,1; retire tile 0's 4 loads, keep tile 1's 4 in
    // flight across the barrier.
    {
        __builtin_amdgcn_global_load_lds(pA0, (lptr3_t)(sAf + d0), 16, 0, 0);
        __builtin_amdgcn_global_load_lds(pA1, (lptr3_t)(sAf + d1), 16, 0, 0);
        __builtin_amdgcn_global_load_lds(pB0, (lptr3_t)(sBf + d0), 16, 0, 0);
        __builtin_amdgcn_global_load_lds(pB1, (lptr3_t)(sBf + d1), 16, 0, 0);
        __builtin_amdgcn_global_load_lds(pA0 + 64, (lptr3_t)(sAf + 16384 + d0), 16, 0, 0);
        __builtin_amdgcn_global_load_lds(pA1 + 64, (lptr3_t)(sAf + 16384 + d1), 16, 0, 0);
        __builtin_amdgcn_global_load_lds(pB0 + 64, (lptr3_t)(sBf + 16384 + d0), 16, 0, 0);
        __builtin_amdgcn_global_load_lds(pB1 + 64, (lptr3_t)(sBf + 16384 + d1), 16, 0, 0);
        asm volatile("s_waitcnt vmcnt(4)" ::: "memory");
        __builtin_amdgcn_sched_barrier(0);
        __builtin_amdgcn_s_barrier();
    }

    int cur = 0, stg = 2;
#pragma unroll 1
    for (int kt = 0; kt < 62; ++kt) {
        const int kb = (kt + 2) * 64;
        gemm_iter<true, 4>(sAf + cur * 16384, sBf + cur * 16384, aoff, boff,
                           acc, pA0 + kb, pA1 + kb, pB0 + kb, pB1 + kb,
                           (lptr3_t)(sAf + stg * 16384 + d0),
                           (lptr3_t)(sAf + stg * 16384 + d1),
                           (lptr3_t)(sBf + stg * 16384 + d0),
                           (lptr3_t)(sBf + stg * 16384 + d1));
        cur = (cur == 2) ? 0 : cur + 1;
        stg = (stg == 2) ? 0 : stg + 1;
    }
    // kt = 62: no staging; drain tile 63's loads.
    gemm_iter<false, 0>(sAf + cur * 16384, sBf + cur * 16384, aoff, boff, acc,
                        pA0, pA1, pB0, pB1, (lptr3_t)(sAf + d0),
                        (lptr3_t)(sAf + d1), (lptr3_t)(sBf + d0),
                        (lptr3_t)(sBf + d1));
    cur = (cur == 2) ? 0 : cur + 1;
    // kt = 63: compute-only.
    gemm_iter<false, -1>(sAf + cur * 16384, sBf + cur * 16384, aoff, boff, acc,
                         pA0, pA1, pB0, pB1, (lptr3_t)(sAf + d0),
                         (lptr3_t)(sAf + d1), (lptr3_t)(sBf + d0),
                         (lptr3_t)(sBf + d1));

    // Epilogue: dequant + store. C/D layout: col = lane&15, row = (lane>>4)*4+reg
    const float ls = 127.0f / fmaxf(__uint_as_float(amax[0]), 1e-12f);
    const float rs = 127.0f / fmaxf(__uint_as_float(amax[1]), 1e-12f);
    const float inv = 1.0f / (ls * rs);
#pragma unroll
    for (int mi = 0; mi < 8; ++mi)
#pragma unroll
        for (int ni = 0; ni < 4; ++ni)
#pragma unroll
            for (int reg = 0; reg < 4; ++reg) {
                const int row = m0 + wm * 128 + mi * 16 + q * 4 + reg;
                const int col = n0 + wn * 64 + ni * 16 + r;
                out[(size_t)row * NROW + col] = (float)acc[mi][ni][reg] * inv;
            }
}

extern "C" void kernel_launch(void* const* d_in, const int* in_sizes, int n_in,
                              void* d_out, int out_size, void* d_ws,
                              size_t ws_size, hipStream_t stream) {
    const float* lhs = (const float*)d_in[0];
    const float* rhs = (const float*)d_in[1];
    float* out = (float*)d_out;

    int8_t* qA = (int8_t*)d_ws;
    int8_t* qBT = qA + (size_t)16 * 1024 * 1024;
    unsigned* amax = (unsigned*)(qBT + (size_t)16 * 1024 * 1024);

    hipMemsetAsync(amax, 0, 8, stream);
    absmax_both_kernel<<<2048, 256, 0, stream>>>(lhs, rhs, amax);
    quant_kernel<<<16384 + 4096, 256, 0, stream>>>(lhs, rhs, qA, qBT, amax);
    gemm_i8_kernel<<<dim3(16, 16), 512, 0, stream>>>(qA, qBT, out, amax);
}